// Round 1
// baseline (2739.561 us; speedup 1.0000x reference)
//
#include <hip/hip_runtime.h>
#include <hip/hip_fp16.h>

// RzLinear: C[N,M] = A[N,K] * W[K,M],  W[k,m] = hw[gidx[k*M+m]]
// Strategy: fp32-accurate GEMM via split-f16 MFMA (3-term: Ah*Wh + Ah*Wl + Al*Wh).
// 128x128 tile, BK=32, 4 waves (2x2), per-wave 64x64 via 4x4 mfma_f32_16x16x32_f16.
// Reg-staged LDS (gather + hi/lo conversion forbids global_load_lds).

#define N_TOK 8192
#define KDIM  4096
#define MDIM  4096

#define BM 128
#define BN 128
#define BK 32
#define LDT 40   // padded leading dim (f16 elems): 80 B row stride, 16B-aligned, bank-balanced

typedef _Float16 f16x8 __attribute__((ext_vector_type(8)));
typedef _Float16 f16x4 __attribute__((ext_vector_type(4)));
typedef float    f32x4 __attribute__((ext_vector_type(4)));

__global__ __launch_bounds__(256, 2)
void rz_linear_splitf16(const float* __restrict__ hw,
                        const float* __restrict__ x,
                        const int*   __restrict__ gidx,
                        float*       __restrict__ out) {
    __shared__ __align__(16) _Float16 Ah[BM][LDT];
    __shared__ __align__(16) _Float16 Al[BM][LDT];
    __shared__ __align__(16) _Float16 Wh[BN][LDT];  // stored k-contiguous: Wh[m][k]
    __shared__ __align__(16) _Float16 Wl[BN][LDT];

    const int tid  = threadIdx.x;
    const int lane = tid & 63;
    const int wave = tid >> 6;
    const int wr   = wave >> 1;       // wave row (n-dim), 0..1
    const int wc   = wave & 1;        // wave col (m-dim), 0..1

    // XCD-aware swizzle (bijective: 2048 % 8 == 0)
    const int bid = blockIdx.x;
    const int swz = (bid & 7) * 256 + (bid >> 3);
    const int n0  = (swz >> 5) * BM;  // 64 n-blocks
    const int m0  = (swz & 31) * BN;  // 32 m-blocks

    // staging coords
    const int a_row = tid >> 3;       // 0..31, +32 per pass
    const int a_kc  = tid & 7;        // float4 slot along k
    const int w_m   = tid & 127;      // W column within tile
    const int w_kg  = tid >> 7;       // 0..1

    const int l15  = lane & 15;
    const int koff = (lane >> 4) * 8; // k offset of this lane's 8-elem fragment slice

    f32x4 acc[4][4];
    #pragma unroll
    for (int i = 0; i < 4; ++i)
        #pragma unroll
        for (int j = 0; j < 4; ++j)
            acc[i][j] = (f32x4)0.0f;

    for (int k0 = 0; k0 < KDIM; k0 += BK) {
        // ---- stage A tile (fp32 -> f16 hi/lo), coalesced float4 loads ----
        #pragma unroll
        for (int p = 0; p < 4; ++p) {
            const int n = a_row + p * 32;
            const float4 v = *reinterpret_cast<const float4*>(
                &x[(size_t)(n0 + n) * KDIM + k0 + a_kc * 4]);
            const _Float16 h0 = (_Float16)v.x, h1 = (_Float16)v.y,
                           h2 = (_Float16)v.z, h3 = (_Float16)v.w;
            f16x4 hv = {h0, h1, h2, h3};
            f16x4 lv = {(_Float16)(v.x - (float)h0), (_Float16)(v.y - (float)h1),
                        (_Float16)(v.z - (float)h2), (_Float16)(v.w - (float)h3)};
            *reinterpret_cast<f16x4*>(&Ah[n][a_kc * 4]) = hv;
            *reinterpret_cast<f16x4*>(&Al[n][a_kc * 4]) = lv;
        }

        // ---- stage W tile: gather-reconstruct, convert, store k-contiguous ----
        #pragma unroll
        for (int q = 0; q < 2; ++q) {
            const int kb = (w_kg + 2 * q) * 8;   // 8 consecutive k per thread
            float wv[8];
            #pragma unroll
            for (int j = 0; j < 8; ++j) {
                const int k = k0 + kb + j;
                const int gi = gidx[k * MDIM + m0 + w_m];  // coalesced in m
                wv[j] = hw[gi];                             // 32-contig per chunk
            }
            f16x8 hv, lv;
            #pragma unroll
            for (int j = 0; j < 8; ++j) {
                const _Float16 h = (_Float16)wv[j];
                hv[j] = h;
                lv[j] = (_Float16)(wv[j] - (float)h);
            }
            *reinterpret_cast<f16x8*>(&Wh[w_m][kb]) = hv;
            *reinterpret_cast<f16x8*>(&Wl[w_m][kb]) = lv;
        }
        __syncthreads();

        // ---- fragment loads (16x ds_read_b128 per wave) + 48 MFMA ----
        f16x8 ah[4], al[4], bh[4], bl[4];
        #pragma unroll
        for (int mi = 0; mi < 4; ++mi) {
            const int r = wr * 64 + mi * 16 + l15;
            ah[mi] = *reinterpret_cast<const f16x8*>(&Ah[r][koff]);
            al[mi] = *reinterpret_cast<const f16x8*>(&Al[r][koff]);
        }
        #pragma unroll
        for (int ni = 0; ni < 4; ++ni) {
            const int c = wc * 64 + ni * 16 + l15;
            bh[ni] = *reinterpret_cast<const f16x8*>(&Wh[c][koff]);
            bl[ni] = *reinterpret_cast<const f16x8*>(&Wl[c][koff]);
        }
        #pragma unroll
        for (int mi = 0; mi < 4; ++mi)
            #pragma unroll
            for (int ni = 0; ni < 4; ++ni) {
                acc[mi][ni] = __builtin_amdgcn_mfma_f32_16x16x32_f16(ah[mi], bh[ni], acc[mi][ni], 0, 0, 0);
                acc[mi][ni] = __builtin_amdgcn_mfma_f32_16x16x32_f16(ah[mi], bl[ni], acc[mi][ni], 0, 0, 0);
                acc[mi][ni] = __builtin_amdgcn_mfma_f32_16x16x32_f16(al[mi], bh[ni], acc[mi][ni], 0, 0, 0);
            }
        __syncthreads();
    }

    // ---- epilogue: C/D layout col=lane&15, row=(lane>>4)*4+r (m89-verified) ----
    #pragma unroll
    for (int mi = 0; mi < 4; ++mi) {
        const int row = n0 + wr * 64 + mi * 16 + (lane >> 4) * 4;
        #pragma unroll
        for (int ni = 0; ni < 4; ++ni) {
            const int col = m0 + wc * 64 + ni * 16 + l15;
            #pragma unroll
            for (int r = 0; r < 4; ++r)
                out[(size_t)(row + r) * MDIM + col] = acc[mi][ni][r];
        }
    }
}

extern "C" void kernel_launch(void* const* d_in, const int* in_sizes, int n_in,
                              void* d_out, int out_size, void* d_ws, size_t ws_size,
                              hipStream_t stream) {
    const float* hw   = (const float*)d_in[0];   // hashed_weights [1<<20]
    const float* x    = (const float*)d_in[1];   // input_v [8192,4096]
    const int*   gidx = (const int*)  d_in[2];   // gather_idx [4096*4096]
    float* out = (float*)d_out;

    const int grid = (N_TOK / BM) * (MDIM / BN); // 64*32 = 2048
    rz_linear_splitf16<<<grid, 256, 0, stream>>>(hw, x, gidx, out);
}

// Round 2
// 953.253 us; speedup vs baseline: 2.8739x; 2.8739x over previous
//
#include <hip/hip_runtime.h>
#include <hip/hip_fp16.h>

// RzLinear: C[N,M] = A[N,K] * W[K,M],  W[k,m] = hw[gidx[k*M+m]]
// Round 2: exploit chunk structure (hash is per-32-elem chunk -> hw reads are
// 128-B contiguous). Kernel 1 materializes W as f16 hi/lo planes, transposed
// [m][k], tiled (8KB contiguous per 128x32 tile), pre-XOR-swizzled (granule
// q ^= (row>>1)&3) into d_ws. Kernel 2 is a split-f16 MFMA GEMM
// (Ah*Wh + Ah*Wl + Al*Wh) with global_load_lds W staging.

#define N_TOK 8192
#define KDIM  4096
#define MDIM  4096

#define BM 128
#define BN 128
#define BK 32

#define PLANE_ELEMS (16777216)        // 4096*4096
#define PLANE_BYTES (33554432ull)     // f16 plane
#define WS_NEEDED   (67108864ull)     // two planes

typedef _Float16 f16x8 __attribute__((ext_vector_type(8)));
typedef _Float16 f16x4 __attribute__((ext_vector_type(4)));
typedef float    f32x4 __attribute__((ext_vector_type(4)));

__device__ __forceinline__ void gload16(const void* g, void* l) {
    __builtin_amdgcn_global_load_lds(
        (const __attribute__((address_space(1))) unsigned int*)g,
        (__attribute__((address_space(3))) unsigned int*)l, 16, 0, 0);
}

// ---------------- kernel 1: W materialization ----------------
// tile ti = mt*128 + kt  (mt: m/128, kt: k/32). Tile = 4096 f16 = 512 granules
// of 16B. Granule p holds logical (r = p>>2, q = (p&3) ^ ((r>>1)&3)):
// m = mt*128 + r, k = kt*32 + q*8 .. +7.
__global__ __launch_bounds__(256)
void rz_prep_w(const float* __restrict__ hw, const int* __restrict__ gidx,
               _Float16* __restrict__ wh, _Float16* __restrict__ wl) {
    __shared__ _Float16 Th[128][32];
    __shared__ _Float16 Tl[128][32];
    const int t  = threadIdx.x;
    const int ti = blockIdx.x;          // 0..4095
    const int mt = ti >> 7;
    const int kt = ti & 127;

    // 128 chunks per tile: chunk c: k-local = c>>2, m-chunk-local = c&3.
    // chunk start = gidx value at chunk boundary (offset o==0 there);
    // hw[start .. start+31] is contiguous by construction.
    #pragma unroll
    for (int it = 0; it < 4; ++it) {
        const int c   = (t >> 3) + it * 32;
        const int kk  = c >> 2;                        // 0..31
        const int mjl = c & 3;
        const int start = gidx[(kt * 32 + kk) * MDIM + (mt * 4 + mjl) * 32];
        const int mo = (t & 7) * 4;
        #pragma unroll
        for (int j = 0; j < 4; ++j) {
            const float v = hw[start + mo + j];        // contiguous, no align req
            const _Float16 h = (_Float16)v;
            Th[mjl * 32 + mo + j][kk] = h;
            Tl[mjl * 32 + mo + j][kk] = (_Float16)(v - (float)h);
        }
    }
    __syncthreads();

    _Float16* whT = wh + (size_t)ti * 4096;
    _Float16* wlT = wl + (size_t)ti * 4096;
    #pragma unroll
    for (int pass = 0; pass < 2; ++pass) {
        const int p = t + pass * 256;
        const int r = p >> 2;
        const int q = (p & 3) ^ ((r >> 1) & 3);        // logical k-granule
        f16x8 hv = *reinterpret_cast<const f16x8*>(&Th[r][q * 8]);
        f16x8 lv = *reinterpret_cast<const f16x8*>(&Tl[r][q * 8]);
        *reinterpret_cast<f16x8*>(&whT[p * 8]) = hv;   // coalesced 16B/lane
        *reinterpret_cast<f16x8*>(&wlT[p * 8]) = lv;
    }
}

// ---------------- kernel 2: split-f16 GEMM ----------------
__global__ __launch_bounds__(256, 2)
void rz_gemm(const float* __restrict__ x,
             const _Float16* __restrict__ wh, const _Float16* __restrict__ wl,
             float* __restrict__ out) {
    __shared__ __align__(16) _Float16 Ah[BM * BK];
    __shared__ __align__(16) _Float16 Al[BM * BK];
    __shared__ __align__(16) _Float16 Bh[BN * BK];
    __shared__ __align__(16) _Float16 Bl[BN * BK];

    const int tid  = threadIdx.x;
    const int lane = tid & 63;
    const int wave = tid >> 6;
    const int wr   = wave >> 1;
    const int wc   = wave & 1;

    const int bid = blockIdx.x;
    const int swz = (bid & 7) * 256 + (bid >> 3);   // bijective: 2048 % 8 == 0
    const int n0  = (swz >> 5) * BM;
    const int mt  = (swz & 31);                     // m-tile index
    const int m0  = mt * BN;

    const int l15  = lane & 15;
    const int qsel = lane >> 4;                     // fragment k-granule 0..3

    // fragment phys element offsets (swizzled), hoisted out of the k-loop
    int a_off[4], b_off[4];
    #pragma unroll
    for (int mi = 0; mi < 4; ++mi) {
        const int rr = wr * 64 + mi * 16 + l15;
        a_off[mi] = rr * 32 + ((qsel ^ ((rr >> 1) & 3)) * 8);
    }
    #pragma unroll
    for (int ni = 0; ni < 4; ++ni) {
        const int cc = wc * 64 + ni * 16 + l15;
        b_off[ni] = cc * 32 + ((qsel ^ ((cc >> 1) & 3)) * 8);
    }

    // A staging coords: granule task p -> r = p>>2 (row), q = p&3 (k-granule)
    const int ar0 = tid >> 2;
    const int aq0 = tid & 3;

    f32x4 acc[4][4];
    #pragma unroll
    for (int i = 0; i < 4; ++i)
        #pragma unroll
        for (int j = 0; j < 4; ++j)
            acc[i][j] = (f32x4)0.0f;

    for (int kt = 0; kt < KDIM / BK; ++kt) {
        // ---- W: 4x global_load_lds dwordx4, linear dest, pre-swizzled src ----
        const _Float16* whT = wh + ((size_t)(mt * 128 + kt)) * 4096;
        const _Float16* wlT = wl + ((size_t)(mt * 128 + kt)) * 4096;
        gload16(whT + tid * 8,         &Bh[tid * 8]);
        gload16(whT + 2048 + tid * 8,  &Bh[2048 + tid * 8]);
        gload16(wlT + tid * 8,         &Bl[tid * 8]);
        gload16(wlT + 2048 + tid * 8,  &Bl[2048 + tid * 8]);

        // ---- A: reg-stage fp32 -> f16 hi/lo, swizzled ds_write ----
        #pragma unroll
        for (int pass = 0; pass < 2; ++pass) {
            const int r = ar0 + pass * 64;
            const int q = aq0;
            const float* src = &x[(size_t)(n0 + r) * KDIM + kt * BK + q * 8];
            const float4 v0 = *reinterpret_cast<const float4*>(src);
            const float4 v1 = *reinterpret_cast<const float4*>(src + 4);
            f16x8 hv, lv;
            const float s[8] = {v0.x, v0.y, v0.z, v0.w, v1.x, v1.y, v1.z, v1.w};
            #pragma unroll
            for (int j = 0; j < 8; ++j) {
                const _Float16 h = (_Float16)s[j];
                hv[j] = h;
                lv[j] = (_Float16)(s[j] - (float)h);
            }
            const int phys = r * 32 + ((q ^ ((r >> 1) & 3)) * 8);
            *reinterpret_cast<f16x8*>(&Ah[phys]) = hv;
            *reinterpret_cast<f16x8*>(&Al[phys]) = lv;
        }
        __syncthreads();   // drains vmcnt (gload_lds) + lgkmcnt (ds_write)

        // ---- fragments + 48 MFMA ----
        f16x8 fah[4], fal[4], fbh[4], fbl[4];
        #pragma unroll
        for (int mi = 0; mi < 4; ++mi) {
            fah[mi] = *reinterpret_cast<const f16x8*>(&Ah[a_off[mi]]);
            fal[mi] = *reinterpret_cast<const f16x8*>(&Al[a_off[mi]]);
        }
        #pragma unroll
        for (int ni = 0; ni < 4; ++ni) {
            fbh[ni] = *reinterpret_cast<const f16x8*>(&Bh[b_off[ni]]);
            fbl[ni] = *reinterpret_cast<const f16x8*>(&Bl[b_off[ni]]);
        }
        #pragma unroll
        for (int mi = 0; mi < 4; ++mi)
            #pragma unroll
            for (int ni = 0; ni < 4; ++ni) {
                acc[mi][ni] = __builtin_amdgcn_mfma_f32_16x16x32_f16(fah[mi], fbh[ni], acc[mi][ni], 0, 0, 0);
                acc[mi][ni] = __builtin_amdgcn_mfma_f32_16x16x32_f16(fah[mi], fbl[ni], acc[mi][ni], 0, 0, 0);
                acc[mi][ni] = __builtin_amdgcn_mfma_f32_16x16x32_f16(fal[mi], fbh[ni], acc[mi][ni], 0, 0, 0);
            }
        __syncthreads();
    }

    // ---- epilogue: C/D layout col=lane&15, row=(lane>>4)*4+r ----
    #pragma unroll
    for (int mi = 0; mi < 4; ++mi) {
        const int row = n0 + wr * 64 + mi * 16 + (lane >> 4) * 4;
        #pragma unroll
        for (int ni = 0; ni < 4; ++ni) {
            const int col = m0 + wc * 64 + ni * 16 + l15;
            #pragma unroll
            for (int r = 0; r < 4; ++r)
                out[(size_t)(row + r) * MDIM + col] = acc[mi][ni][r];
        }
    }
}

// ---------------- fallback (round-1 kernel, known-correct) ----------------
#define LDT 40
__global__ __launch_bounds__(256, 2)
void rz_linear_splitf16_fb(const float* __restrict__ hw,
                           const float* __restrict__ x,
                           const int*   __restrict__ gidx,
                           float*       __restrict__ out) {
    __shared__ __align__(16) _Float16 Ah[BM][LDT];
    __shared__ __align__(16) _Float16 Al[BM][LDT];
    __shared__ __align__(16) _Float16 Wh[BN][LDT];
    __shared__ __align__(16) _Float16 Wl[BN][LDT];
    const int tid  = threadIdx.x;
    const int lane = tid & 63;
    const int wave = tid >> 6;
    const int wr   = wave >> 1;
    const int wc   = wave & 1;
    const int bid = blockIdx.x;
    const int swz = (bid & 7) * 256 + (bid >> 3);
    const int n0  = (swz >> 5) * BM;
    const int m0  = (swz & 31) * BN;
    const int a_row = tid >> 3;
    const int a_kc  = tid & 7;
    const int w_m   = tid & 127;
    const int w_kg  = tid >> 7;
    const int l15  = lane & 15;
    const int koff = (lane >> 4) * 8;
    f32x4 acc[4][4];
    #pragma unroll
    for (int i = 0; i < 4; ++i)
        #pragma unroll
        for (int j = 0; j < 4; ++j) acc[i][j] = (f32x4)0.0f;
    for (int k0 = 0; k0 < KDIM; k0 += BK) {
        #pragma unroll
        for (int p = 0; p < 4; ++p) {
            const int n = a_row + p * 32;
            const float4 v = *reinterpret_cast<const float4*>(
                &x[(size_t)(n0 + n) * KDIM + k0 + a_kc * 4]);
            const _Float16 h0 = (_Float16)v.x, h1 = (_Float16)v.y,
                           h2 = (_Float16)v.z, h3 = (_Float16)v.w;
            f16x4 hv = {h0, h1, h2, h3};
            f16x4 lv = {(_Float16)(v.x - (float)h0), (_Float16)(v.y - (float)h1),
                        (_Float16)(v.z - (float)h2), (_Float16)(v.w - (float)h3)};
            *reinterpret_cast<f16x4*>(&Ah[n][a_kc * 4]) = hv;
            *reinterpret_cast<f16x4*>(&Al[n][a_kc * 4]) = lv;
        }
        #pragma unroll
        for (int q = 0; q < 2; ++q) {
            const int kb = (w_kg + 2 * q) * 8;
            float wv[8];
            #pragma unroll
            for (int j = 0; j < 8; ++j) {
                const int k = k0 + kb + j;
                const int gi = gidx[k * MDIM + m0 + w_m];
                wv[j] = hw[gi];
            }
            f16x8 hv, lv;
            #pragma unroll
            for (int j = 0; j < 8; ++j) {
                const _Float16 h = (_Float16)wv[j];
                hv[j] = h;
                lv[j] = (_Float16)(wv[j] - (float)h);
            }
            *reinterpret_cast<f16x8*>(&Wh[w_m][kb]) = hv;
            *reinterpret_cast<f16x8*>(&Wl[w_m][kb]) = lv;
        }
        __syncthreads();
        f16x8 ah[4], al[4], bh[4], bl[4];
        #pragma unroll
        for (int mi = 0; mi < 4; ++mi) {
            const int r = wr * 64 + mi * 16 + l15;
            ah[mi] = *reinterpret_cast<const f16x8*>(&Ah[r][koff]);
            al[mi] = *reinterpret_cast<const f16x8*>(&Al[r][koff]);
        }
        #pragma unroll
        for (int ni = 0; ni < 4; ++ni) {
            const int c = wc * 64 + ni * 16 + l15;
            bh[ni] = *reinterpret_cast<const f16x8*>(&Wh[c][koff]);
            bl[ni] = *reinterpret_cast<const f16x8*>(&Wl[c][koff]);
        }
        #pragma unroll
        for (int mi = 0; mi < 4; ++mi)
            #pragma unroll
            for (int ni = 0; ni < 4; ++ni) {
                acc[mi][ni] = __builtin_amdgcn_mfma_f32_16x16x32_f16(ah[mi], bh[ni], acc[mi][ni], 0, 0, 0);
                acc[mi][ni] = __builtin_amdgcn_mfma_f32_16x16x32_f16(ah[mi], bl[ni], acc[mi][ni], 0, 0, 0);
                acc[mi][ni] = __builtin_amdgcn_mfma_f32_16x16x32_f16(al[mi], bh[ni], acc[mi][ni], 0, 0, 0);
            }
        __syncthreads();
    }
    #pragma unroll
    for (int mi = 0; mi < 4; ++mi) {
        const int row = n0 + wr * 64 + mi * 16 + (lane >> 4) * 4;
        #pragma unroll
        for (int ni = 0; ni < 4; ++ni) {
            const int col = m0 + wc * 64 + ni * 16 + l15;
            #pragma unroll
            for (int r = 0; r < 4; ++r)
                out[(size_t)(row + r) * MDIM + col] = acc[mi][ni][r];
        }
    }
}

extern "C" void kernel_launch(void* const* d_in, const int* in_sizes, int n_in,
                              void* d_out, int out_size, void* d_ws, size_t ws_size,
                              hipStream_t stream) {
    const float* hw   = (const float*)d_in[0];
    const float* x    = (const float*)d_in[1];
    const int*   gidx = (const int*)  d_in[2];
    float* out = (float*)d_out;

    if (ws_size >= WS_NEEDED) {
        _Float16* whp = (_Float16*)d_ws;
        _Float16* wlp = (_Float16*)((char*)d_ws + PLANE_BYTES);
        rz_prep_w<<<4096, 256, 0, stream>>>(hw, gidx, whp, wlp);
        rz_gemm<<<2048, 256, 0, stream>>>(x, whp, wlp, out);
    } else {
        rz_linear_splitf16_fb<<<2048, 256, 0, stream>>>(hw, x, gidx, out);
    }
}